// Round 1
// baseline (243.511 us; speedup 1.0000x reference)
//
#include <hip/hip_runtime.h>
#include <hip/hip_fp16.h>

typedef _Float16 f16;
typedef f16 f16x8 __attribute__((ext_vector_type(8)));
typedef float f32x4 __attribute__((ext_vector_type(4)));

constexpr int T = 64;
constexpr int H = 4096;
constexpr int I = 11008;
constexpr int GS = 128;
constexpr int GH = 32;   // H / GS
constexpr int GI = 86;   // I / GS

// ---------------- x f32 -> f16 ----------------
__global__ __launch_bounds__(256) void k_cvt(const float* __restrict__ x,
                                             f16* __restrict__ y) {
    int i = blockIdx.x * 256 + threadIdx.x;
    y[i] = (f16)x[i];
}

// dequant 8 consecutive int32 quants -> 8 fp16 weights: w = q*s - zp*s
__device__ __forceinline__ f16x8 dq8(const int* __restrict__ qp, float sv, float zv) {
    int4 a = *(const int4*)qp;
    int4 b = *(const int4*)(qp + 4);
    f16x8 r;
    auto p0 = __builtin_amdgcn_cvt_pkrtz((float)a.x * sv - zv, (float)a.y * sv - zv);
    auto p1 = __builtin_amdgcn_cvt_pkrtz((float)a.z * sv - zv, (float)a.w * sv - zv);
    auto p2 = __builtin_amdgcn_cvt_pkrtz((float)b.x * sv - zv, (float)b.y * sv - zv);
    auto p3 = __builtin_amdgcn_cvt_pkrtz((float)b.z * sv - zv, (float)b.w * sv - zv);
    r[0] = p0[0]; r[1] = p0[1]; r[2] = p1[0]; r[3] = p1[1];
    r[4] = p2[0]; r[5] = p2[1]; r[6] = p3[0]; r[7] = p3[1];
    return r;
}

// ---------------- fused gate/up: h = silu(x@w1^T) * (x@w3^T), fp16 out ----------------
// grid: I/16 blocks, 128 threads (2 waves). wave0 -> w1, wave1 -> w3, same 16 rows.
__global__ __launch_bounds__(128) void k_gateup(
    const f16* __restrict__ x16,
    const int* __restrict__ q1, const float* __restrict__ s1, const int* __restrict__ zp1,
    const int* __restrict__ q3, const float* __restrict__ s3, const int* __restrict__ zp3,
    f16* __restrict__ hbuf)
{
    const int wave = threadIdx.x >> 6;
    const int lane = threadIdx.x & 63;
    const int lo = lane & 15, hi = lane >> 4;
    const int rb = blockIdx.x * 16;
    const int row = rb + lo;           // weight row (N index)

    const int*   q  = wave ? q3 : q1;
    const float* s  = wave ? s3 : s1;
    const int*   zp = wave ? zp3 : zp1;

    const int*   qrow  = q  + (size_t)row * H;
    const float* srow  = s  + (size_t)row * GH;
    const int*   zprow = zp + (size_t)row * GH;

    f32x4 acc[4] = {};

    for (int g = 0; g < GH; ++g) {
        float sv = srow[g];
        float zv = (float)zprow[g] * sv;
        int kb = g * GS + hi * 8;
        #pragma unroll
        for (int sub = 0; sub < 4; ++sub) {
            int k = kb + sub * 32;
            f16x8 bfrag = dq8(qrow + k, sv, zv);
            #pragma unroll
            for (int mt = 0; mt < 4; ++mt) {
                f16x8 afrag = *(const f16x8*)(x16 + (size_t)(mt * 16 + lo) * H + k);
                acc[mt] = __builtin_amdgcn_mfma_f32_16x16x32_f16(afrag, bfrag, acc[mt], 0, 0, 0);
            }
        }
    }

    // D layout: col(N) = lane&15, row(M=token) = 4*(lane>>4) + reg
    __shared__ float xs[2][T][17];
    #pragma unroll
    for (int mt = 0; mt < 4; ++mt)
        #pragma unroll
        for (int j = 0; j < 4; ++j)
            xs[wave][mt * 16 + hi * 4 + j][lo] = acc[mt][j];
    __syncthreads();

    for (int e = threadIdx.x; e < T * 16; e += 128) {
        int t = e >> 4, c = e & 15;
        float g1v = xs[0][t][c];
        float g3v = xs[1][t][c];
        float sil = g1v / (1.f + __expf(-g1v));
        hbuf[(size_t)t * I + rb + c] = (f16)(sil * g3v);
    }
}

// ---------------- down proj partials: part[y] += h @ w2^T (K-split by groups) ----------------
// grid: (H/32, 4), 128 threads (2 waves); wave w -> 16 rows.
__global__ __launch_bounds__(128) void k_down(
    const f16* __restrict__ hbuf,
    const int* __restrict__ q2, const float* __restrict__ s2, const int* __restrict__ zp2,
    float* __restrict__ part)
{
    const int wave = threadIdx.x >> 6;
    const int lane = threadIdx.x & 63;
    const int lo = lane & 15, hi = lane >> 4;
    const int row = blockIdx.x * 32 + wave * 16 + lo;   // weight row = output column (H)
    const int y = blockIdx.y;
    const int g0 = (y * GI) >> 2, g1 = ((y + 1) * GI) >> 2;

    const int*   qrow  = q2  + (size_t)row * I;
    const float* srow  = s2  + (size_t)row * GI;
    const int*   zprow = zp2 + (size_t)row * GI;

    f32x4 acc[4] = {};
    for (int g = g0; g < g1; ++g) {
        float sv = srow[g];
        float zv = (float)zprow[g] * sv;
        int kb = g * GS + hi * 8;
        #pragma unroll
        for (int sub = 0; sub < 4; ++sub) {
            int k = kb + sub * 32;
            f16x8 bfrag = dq8(qrow + k, sv, zv);
            #pragma unroll
            for (int mt = 0; mt < 4; ++mt) {
                f16x8 afrag = *(const f16x8*)(hbuf + (size_t)(mt * 16 + lo) * I + k);
                acc[mt] = __builtin_amdgcn_mfma_f32_16x16x32_f16(afrag, bfrag, acc[mt], 0, 0, 0);
            }
        }
    }

    float* p = part + (size_t)y * T * H;
    #pragma unroll
    for (int mt = 0; mt < 4; ++mt)
        #pragma unroll
        for (int j = 0; j < 4; ++j)
            p[(size_t)(mt * 16 + hi * 4 + j) * H + row] = acc[mt][j];
}

// ---------------- reduce 4 partials -> out ----------------
__global__ __launch_bounds__(256) void k_reduce(const float* __restrict__ part,
                                                float* __restrict__ out) {
    int i = blockIdx.x * 256 + threadIdx.x;
    constexpr int N = T * H;
    out[i] = part[i] + part[N + i] + part[2 * N + i] + part[3 * N + i];
}

extern "C" void kernel_launch(void* const* d_in, const int* in_sizes, int n_in,
                              void* d_out, int out_size, void* d_ws, size_t ws_size,
                              hipStream_t stream) {
    const float* x   = (const float*)d_in[0];
    const int*   q1  = (const int*)d_in[1];
    const float* s1  = (const float*)d_in[2];
    const int*   zp1 = (const int*)d_in[3];
    const int*   q3  = (const int*)d_in[4];
    const float* s3  = (const float*)d_in[5];
    const int*   zp3 = (const int*)d_in[6];
    const int*   q2  = (const int*)d_in[7];
    const float* s2  = (const float*)d_in[8];
    const int*   zp2 = (const int*)d_in[9];

    char* ws = (char*)d_ws;
    f16*   x16  = (f16*)ws;                              // 524288 B
    f16*   hbuf = (f16*)(ws + 524288);                   // 1409024 B
    float* part = (float*)(ws + 524288 + 1409024);       // 4194304 B

    k_cvt<<<T * H / 256, 256, 0, stream>>>(x, x16);
    k_gateup<<<I / 16, 128, 0, stream>>>(x16, q1, s1, zp1, q3, s3, zp3, hbuf);
    k_down<<<dim3(H / 32, 4), 128, 0, stream>>>(hbuf, q2, s2, zp2, part);
    k_reduce<<<T * H / 256, 256, 0, stream>>>(part, (float*)d_out);
}